// Round 7
// baseline (285.518 us; speedup 1.0000x reference)
//
#include <hip/hip_runtime.h>
#include <hip/hip_bf16.h>

#define NNODES 50000
#define NEDGES 800000
#define DD 128
#define EDD 32

#define SNB ((NNODES + 255) / 256)   // 196 scan blocks

typedef short bfrag __attribute__((ext_vector_type(8)));   // 8 bf16 = 4 VGPRs
typedef float fx4  __attribute__((ext_vector_type(4)));    // MFMA accumulator

// packed-weight slot offsets (in units of 16B slots)
#define PW_CONV 0        // 9 kb * 8 t * 64
#define PW_Z    4608     // 8 * 8 * 64
#define PW_R    8704
#define PW_H    12800
#define PW_TOT  16896

__device__ __forceinline__ unsigned short f2bf(float f) {
    unsigned u = __float_as_uint(f);
    u += 0x7fffu + ((u >> 16) & 1u);      // round-to-nearest-even
    return (unsigned short)(u >> 16);
}
__device__ __forceinline__ float bf2f(unsigned short s) {
    return __uint_as_float(((unsigned)s) << 16);
}
__device__ __forceinline__ float fast_sigmoid(float x) {
    return 1.0f / (1.0f + __expf(-x));
}
__device__ __forceinline__ float fast_tanh(float x) {
    return 1.0f - 2.0f / (__expf(2.0f * x) + 1.0f);
}

// ---------------- CSR build ----------------
__global__ __launch_bounds__(256) void count_kernel(const int* __restrict__ ei,
                                                    int* __restrict__ deg) {
    int e = blockIdx.x * 256 + threadIdx.x;
    if (e < NEDGES) atomicAdd(&deg[__builtin_nontemporal_load(&ei[NEDGES + e])], 1);
}

// hierarchical scan, phase 1: per-block (256-elem) reduce
__global__ __launch_bounds__(256) void scan_reduce(const int* __restrict__ deg,
                                                   int* __restrict__ bsum) {
    __shared__ int s[256];
    int t = threadIdx.x;
    int i = blockIdx.x * 256 + t;
    s[t] = (i < NNODES) ? deg[i] : 0;
    __syncthreads();
    for (int d = 128; d > 0; d >>= 1) {
        if (t < d) s[t] += s[t + d];
        __syncthreads();
    }
    if (t == 0) bsum[blockIdx.x] = s[0];
}

// phase 2: exclusive scan of the 196 block sums (single 256-thread block)
__global__ __launch_bounds__(256) void scan_bsum(int* __restrict__ bsum,
                                                 int* __restrict__ off) {
    __shared__ int s[256];
    int t = threadIdx.x;
    int v = (t < SNB) ? bsum[t] : 0;
    s[t] = v;
    __syncthreads();
    for (int d = 1; d < 256; d <<= 1) {
        int u = (t >= d) ? s[t - d] : 0;
        __syncthreads();
        s[t] += u;
        __syncthreads();
    }
    if (t < SNB) bsum[t] = s[t] - v;      // exclusive base per block
    if (t == 255) off[NNODES] = s[255];   // total = NEDGES
}

// phase 3: per-block exclusive scan + base, write off & cursor
__global__ __launch_bounds__(256) void scan_final(const int* __restrict__ deg,
                                                  const int* __restrict__ bsum,
                                                  int* __restrict__ off,
                                                  int* __restrict__ cursor) {
    __shared__ int s[256];
    int t = threadIdx.x;
    int i = blockIdx.x * 256 + t;
    int v = (i < NNODES) ? deg[i] : 0;
    s[t] = v;
    __syncthreads();
    for (int d = 1; d < 256; d <<= 1) {
        int u = (t >= d) ? s[t - d] : 0;
        __syncthreads();
        s[t] += u;
        __syncthreads();
    }
    if (i < NNODES) {
        int e = bsum[blockIdx.x] + s[t] - v;
        off[i] = e;
        cursor[i] = e;
    }
}

__global__ __launch_bounds__(256) void fill_kernel(const int* __restrict__ ei,
                                                   int* __restrict__ cursor,
                                                   long long* __restrict__ csr) {
    int e = blockIdx.x * 256 + threadIdx.x;
    if (e < NEDGES) {
        int dst = __builtin_nontemporal_load(&ei[NEDGES + e]);
        int src = __builtin_nontemporal_load(&ei[e]);
        int p = atomicAdd(&cursor[dst], 1);
        __builtin_nontemporal_store((long long)(unsigned)src | ((long long)e << 32), &csr[p]);
    }
}

// ---------------- gather aggregation: one wave per node, predicated 16-deep ----------------
__global__ __launch_bounds__(256) void aggregate_kernel(
    const float* __restrict__ x, const float* __restrict__ ef,
    const long long* __restrict__ csr, const int* __restrict__ off,
    short* __restrict__ Sb, short* __restrict__ Tb)
{
    int n = (int)((blockIdx.x * blockDim.x + threadIdx.x) >> 6);
    int lane = threadIdx.x & 63;
    if (n >= NNODES) return;
    int i0 = off[n], i1 = off[n + 1];
    float2 acc = make_float2(0.0f, 0.0f);
    float accT = 0.0f;
    // predicated 16-deep: every batch has 16 loads in flight; tail lanes clamp
    // to the last valid edge (L1-hit) and contribute exact 0.
    for (int i = i0; i < i1; i += 16) {
        long long c[16];
        #pragma unroll
        for (int u = 0; u < 16; u++) {
            int idx = i + u;
            idx = (idx < i1) ? idx : (i1 - 1);
            c[u] = __builtin_nontemporal_load(&csr[idx]);
        }
        float2 v[16];
        #pragma unroll
        for (int u = 0; u < 16; u++) {
            int src = (int)(unsigned)c[u];
            v[u] = *reinterpret_cast<const float2*>(&x[(size_t)src * DD + lane * 2]);
        }
        float e[16];
        #pragma unroll
        for (int u = 0; u < 16; u++) {
            int eid = (int)(c[u] >> 32);
            e[u] = (lane < EDD) ? __builtin_nontemporal_load(&ef[(size_t)eid * EDD + lane]) : 0.0f;
        }
        #pragma unroll
        for (int u = 0; u < 16; u++) {
            bool ok = (i + u) < i1;
            acc.x += ok ? v[u].x : 0.0f;
            acc.y += ok ? v[u].y : 0.0f;
            accT  += ok ? e[u]   : 0.0f;
        }
    }
    unsigned pk = ((unsigned)f2bf(acc.y) << 16) | (unsigned)f2bf(acc.x);
    reinterpret_cast<unsigned*>(Sb)[(size_t)n * 64 + lane] = pk;
    if (lane < EDD)
        reinterpret_cast<unsigned short*>(Tb)[(size_t)n * EDD + lane] = f2bf(accT);
}

// ---------------- weight pre-pack into bf16 fragment layout ----------------
__global__ __launch_bounds__(256) void pack_weights(
    const float* __restrict__ Wmsg, const float* __restrict__ Wskip,
    const float* __restrict__ Wz, const float* __restrict__ Wr,
    const float* __restrict__ Wh, bfrag* __restrict__ pW)
{
    int id = blockIdx.x * 256 + threadIdx.x;
    if (id >= PW_TOT) return;
    const float* W = nullptr;
    int rem;
    bool conv = false;
    if (id < PW_Z)      { rem = id;           conv = true; }
    else if (id < PW_R) { rem = id - PW_Z;    W = Wz; }
    else if (id < PW_H) { rem = id - PW_R;    W = Wr; }
    else                { rem = id - PW_H;    W = Wh; }
    int kb   = rem >> 9;
    int t    = (rem >> 6) & 7;
    int lane = rem & 63;
    int col  = t * 16 + (lane & 15);
    int k0   = kb * 32 + ((lane >> 4) << 3);
    bfrag v;
    #pragma unroll
    for (int j = 0; j < 8; j++) {
        int k = k0 + j;
        float w;
        if (conv) w = (k < 160) ? Wmsg[k * DD + col] : Wskip[(k - 160) * DD + col];
        else      w = W[k * DD + col];
        v[j] = (short)f2bf(w);
    }
    pW[id] = v;
}

// ---------------- fused MFMA node kernel ----------------
__global__ __launch_bounds__(256) void node_mfma(
    const float* __restrict__ x, const float* __restrict__ H,
    const short* __restrict__ Sb, const short* __restrict__ Tb,
    const bfrag* __restrict__ pW,
    const float* __restrict__ bconv, const float* __restrict__ bskip,
    const float* __restrict__ bz, const float* __restrict__ br,
    const float* __restrict__ bh,
    float* __restrict__ out)
{
    __shared__ short lclA[9 * 2 * 64 * 8];   // 18432 B
    __shared__ short lclG[4 * 2 * 64 * 8];   //  8192 B
    const int tid = threadIdx.x;
    const int n0 = blockIdx.x * 32;

    for (int s = tid; s < 1152; s += 256) {
        int kb = s >> 7, mm = (s >> 6) & 1, cb = (s >> 4) & 3, r16 = s & 15;
        int row = mm * 16 + r16, gn = n0 + row;
        int k0 = kb * 32 + cb * 8;
        bfrag v;
        if (gn < NNODES) {
            if (k0 < 128) {
                v = *(const bfrag*)&Sb[(size_t)gn * DD + k0];
            } else if (k0 < 160) {
                v = *(const bfrag*)&Tb[(size_t)gn * EDD + (k0 - 128)];
            } else {
                const float* src = &x[(size_t)gn * DD + (k0 - 160)];
                float4 p0 = *(const float4*)src;
                float4 p1 = *(const float4*)(src + 4);
                v[0] = (short)f2bf(p0.x); v[1] = (short)f2bf(p0.y);
                v[2] = (short)f2bf(p0.z); v[3] = (short)f2bf(p0.w);
                v[4] = (short)f2bf(p1.x); v[5] = (short)f2bf(p1.y);
                v[6] = (short)f2bf(p1.z); v[7] = (short)f2bf(p1.w);
            }
        } else {
            #pragma unroll
            for (int j = 0; j < 8; j++) v[j] = 0;
        }
        *(bfrag*)&lclA[((kb * 2 + mm) * 64 + (r16 | (cb << 4))) * 8] = v;
    }
    for (int s = tid; s < 512; s += 256) {
        int kb = s >> 7, mm = (s >> 6) & 1, cb = (s >> 4) & 3, r16 = s & 15;
        int row = mm * 16 + r16, gn = n0 + row;
        int c0 = kb * 32 + cb * 8;
        bfrag v;
        if (gn < NNODES) {
            const float* src = &H[(size_t)gn * DD + c0];
            float4 p0 = *(const float4*)src;
            float4 p1 = *(const float4*)(src + 4);
            v[0] = (short)f2bf(p0.x); v[1] = (short)f2bf(p0.y);
            v[2] = (short)f2bf(p0.z); v[3] = (short)f2bf(p0.w);
            v[4] = (short)f2bf(p1.x); v[5] = (short)f2bf(p1.y);
            v[6] = (short)f2bf(p1.z); v[7] = (short)f2bf(p1.w);
        } else {
            #pragma unroll
            for (int j = 0; j < 8; j++) v[j] = 0;
        }
        *(bfrag*)&lclG[((kb * 2 + mm) * 64 + (r16 | (cb << 4))) * 8] = v;
    }
    __syncthreads();

    const int w    = tid >> 6;
    const int lane = tid & 63;
    const int m    = w & 1;
    const int ng   = (w >> 1) * 4;
    const int lc   = lane & 15;
    const int lr4  = (lane >> 4) * 4;

    fx4 acc[4];
    #pragma unroll
    for (int t = 0; t < 4; t++) {
        int c = (ng + t) * 16 + lc;
        float b = bconv[c] + bskip[c];
        acc[t] = (fx4){b, b, b, b};
    }
    #pragma unroll
    for (int kb = 0; kb < 9; kb++) {
        bfrag a = *(const bfrag*)&lclA[((kb * 2 + m) * 64 + lane) * 8];
        #pragma unroll
        for (int t = 0; t < 4; t++) {
            bfrag b = pW[PW_CONV + (kb * 8 + ng + t) * 64 + lane];
            acc[t] = __builtin_amdgcn_mfma_f32_16x16x32_bf16(a, b, acc[t], 0, 0, 0);
        }
    }
    __syncthreads();

    #pragma unroll
    for (int t = 0; t < 4; t++) {
        int c  = (ng + t) * 16 + lc;
        int kb = c >> 5;
        int cb = (c >> 3) & 3;
        int j  = c & 7;
        #pragma unroll
        for (int reg = 0; reg < 4; reg++) {
            int row16 = lr4 + reg;
            float hv = fmaxf(acc[t][reg], 0.0f);
            lclA[((kb * 2 + m) * 64 + (row16 | (cb << 4))) * 8 + j] = (short)f2bf(hv);
        }
    }
    __syncthreads();

    fx4 az[4], ar[4];
    #pragma unroll
    for (int t = 0; t < 4; t++) {
        int c = (ng + t) * 16 + lc;
        float b1 = bz[c], b2 = br[c];
        az[t] = (fx4){b1, b1, b1, b1};
        ar[t] = (fx4){b2, b2, b2, b2};
    }
    #pragma unroll
    for (int kb = 0; kb < 8; kb++) {
        bfrag a = (kb < 4)
            ? *(const bfrag*)&lclA[((kb * 2 + m) * 64 + lane) * 8]
            : *(const bfrag*)&lclG[(((kb - 4) * 2 + m) * 64 + lane) * 8];
        #pragma unroll
        for (int t = 0; t < 4; t++) {
            bfrag wz = pW[PW_Z + (kb * 8 + ng + t) * 64 + lane];
            bfrag wr = pW[PW_R + (kb * 8 + ng + t) * 64 + lane];
            az[t] = __builtin_amdgcn_mfma_f32_16x16x32_bf16(a, wz, az[t], 0, 0, 0);
            ar[t] = __builtin_amdgcn_mfma_f32_16x16x32_bf16(a, wr, ar[t], 0, 0, 0);
        }
    }

    float zv[4][4], Hv[4][4], rHv[4][4];
    #pragma unroll
    for (int t = 0; t < 4; t++) {
        int c  = (ng + t) * 16 + lc;
        int kb = c >> 5;
        int cb = (c >> 3) & 3;
        int j  = c & 7;
        #pragma unroll
        for (int reg = 0; reg < 4; reg++) {
            int row16 = lr4 + reg;
            zv[t][reg] = fast_sigmoid(az[t][reg]);
            float rv = fast_sigmoid(ar[t][reg]);
            float hH = bf2f((unsigned short)lclG[((kb * 2 + m) * 64 + (row16 | (cb << 4))) * 8 + j]);
            Hv[t][reg]  = hH;
            rHv[t][reg] = rv * hH;
        }
    }
    __syncthreads();

    #pragma unroll
    for (int t = 0; t < 4; t++) {
        int c  = (ng + t) * 16 + lc;
        int kb = c >> 5;
        int cb = (c >> 3) & 3;
        int j  = c & 7;
        #pragma unroll
        for (int reg = 0; reg < 4; reg++) {
            int row16 = lr4 + reg;
            lclG[((kb * 2 + m) * 64 + (row16 | (cb << 4))) * 8 + j] = (short)f2bf(rHv[t][reg]);
        }
    }
    __syncthreads();

    fx4 ah[4];
    #pragma unroll
    for (int t = 0; t < 4; t++) {
        int c = (ng + t) * 16 + lc;
        float b = bh[c];
        ah[t] = (fx4){b, b, b, b};
    }
    #pragma unroll
    for (int kb = 0; kb < 8; kb++) {
        bfrag a = (kb < 4)
            ? *(const bfrag*)&lclA[((kb * 2 + m) * 64 + lane) * 8]
            : *(const bfrag*)&lclG[(((kb - 4) * 2 + m) * 64 + lane) * 8];
        #pragma unroll
        for (int t = 0; t < 4; t++) {
            bfrag wh = pW[PW_H + (kb * 8 + ng + t) * 64 + lane];
            ah[t] = __builtin_amdgcn_mfma_f32_16x16x32_bf16(a, wh, ah[t], 0, 0, 0);
        }
    }

    #pragma unroll
    for (int reg = 0; reg < 4; reg++) {
        int row = m * 16 + lr4 + reg;
        int gn = n0 + row;
        if (gn < NNODES) {
            #pragma unroll
            for (int t = 0; t < 4; t++) {
                int c = (ng + t) * 16 + lc;
                float ht = fast_tanh(ah[t][reg]);
                float zz = zv[t][reg];
                out[(size_t)gn * DD + c] = zz * Hv[t][reg] + (1.0f - zz) * ht;
            }
        }
    }
}

extern "C" void kernel_launch(void* const* d_in, const int* in_sizes, int n_in,
                              void* d_out, int out_size, void* d_ws, size_t ws_size,
                              hipStream_t stream) {
    const float* x     = (const float*)d_in[0];
    const float* ef    = (const float*)d_in[1];
    const float* Hst   = (const float*)d_in[2];
    const int*   ei    = (const int*)d_in[3];
    const float* Wmsg  = (const float*)d_in[4];
    const float* bconv = (const float*)d_in[5];
    const float* Wskip = (const float*)d_in[6];
    const float* bskip = (const float*)d_in[7];
    const float* Wz    = (const float*)d_in[8];
    const float* bz    = (const float*)d_in[9];
    const float* Wr    = (const float*)d_in[10];
    const float* br    = (const float*)d_in[11];
    const float* Wh    = (const float*)d_in[12];
    const float* bh    = (const float*)d_in[13];
    float* out = (float*)d_out;

    // workspace layout (16B alignment maintained)
    bfrag* pW  = (bfrag*)d_ws;                               // 270336 B
    short* Sb  = (short*)((char*)d_ws + PW_TOT * 16);        // [N,128] bf16 12.8 MB
    short* Tb  = Sb + (size_t)NNODES * DD;                   // [N,32]  bf16  3.2 MB
    int*   deg = (int*)(Tb + (size_t)NNODES * EDD);          // [N]
    int*   off = deg + NNODES;                               // [N+1]
    int*   cur = off + NNODES + 1;                           // [N+1]
    int*   bsum = cur + NNODES + 1;                          // [256]
    long long* csr = (long long*)(bsum + 256);               // [E] 6.4 MB (8B-aligned)

    (void)hipMemsetAsync(deg, 0, NNODES * sizeof(int), stream);

    pack_weights<<<(PW_TOT + 255) / 256, 256, 0, stream>>>(Wmsg, Wskip, Wz, Wr, Wh, pW);

    int nbE = (NEDGES + 255) / 256;
    count_kernel<<<nbE, 256, 0, stream>>>(ei, deg);
    scan_reduce<<<SNB, 256, 0, stream>>>(deg, bsum);
    scan_bsum<<<1, 256, 0, stream>>>(bsum, off);
    scan_final<<<SNB, 256, 0, stream>>>(deg, bsum, off, cur);
    fill_kernel<<<nbE, 256, 0, stream>>>(ei, cur, csr);

    int nbA = (NNODES * 64 + 255) / 256;
    aggregate_kernel<<<nbA, 256, 0, stream>>>(x, ef, csr, off, Sb, Tb);

    int nb2 = (NNODES + 31) / 32;
    node_mfma<<<nb2, 256, 0, stream>>>(x, Hst, Sb, Tb, pW, bconv, bskip,
                                       bz, br, bh, out);
}

// Round 8
// 261.905 us; speedup vs baseline: 1.0902x; 1.0902x over previous
//
#include <hip/hip_runtime.h>
#include <hip/hip_bf16.h>

#define NNODES 50000
#define NEDGES 800000
#define DD 128
#define EDD 32

#define SNB ((NNODES + 255) / 256)   // 196 scan blocks

typedef short bfrag __attribute__((ext_vector_type(8)));   // 8 bf16 = 4 VGPRs
typedef float fx4  __attribute__((ext_vector_type(4)));    // MFMA accumulator

// packed-weight slot offsets (in units of 16B slots)
#define PW_CONV 0        // 9 kb * 8 t * 64
#define PW_Z    4608     // 8 * 8 * 64
#define PW_R    8704
#define PW_H    12800
#define PW_TOT  16896

__device__ __forceinline__ unsigned short f2bf(float f) {
    unsigned u = __float_as_uint(f);
    u += 0x7fffu + ((u >> 16) & 1u);      // round-to-nearest-even
    return (unsigned short)(u >> 16);
}
__device__ __forceinline__ float bf2f(unsigned short s) {
    return __uint_as_float(((unsigned)s) << 16);
}
__device__ __forceinline__ float fast_sigmoid(float x) {
    return 1.0f / (1.0f + __expf(-x));
}
__device__ __forceinline__ float fast_tanh(float x) {
    return 1.0f - 2.0f / (__expf(2.0f * x) + 1.0f);
}

// ---------------- CSR build ----------------
__global__ __launch_bounds__(256) void count_kernel(const int* __restrict__ ei,
                                                    int* __restrict__ deg) {
    int e = blockIdx.x * 256 + threadIdx.x;
    if (e < NEDGES) atomicAdd(&deg[__builtin_nontemporal_load(&ei[NEDGES + e])], 1);
}

__global__ __launch_bounds__(256) void scan_reduce(const int* __restrict__ deg,
                                                   int* __restrict__ bsum) {
    __shared__ int s[256];
    int t = threadIdx.x;
    int i = blockIdx.x * 256 + t;
    s[t] = (i < NNODES) ? deg[i] : 0;
    __syncthreads();
    for (int d = 128; d > 0; d >>= 1) {
        if (t < d) s[t] += s[t + d];
        __syncthreads();
    }
    if (t == 0) bsum[blockIdx.x] = s[0];
}

__global__ __launch_bounds__(256) void scan_bsum(int* __restrict__ bsum,
                                                 int* __restrict__ off) {
    __shared__ int s[256];
    int t = threadIdx.x;
    int v = (t < SNB) ? bsum[t] : 0;
    s[t] = v;
    __syncthreads();
    for (int d = 1; d < 256; d <<= 1) {
        int u = (t >= d) ? s[t - d] : 0;
        __syncthreads();
        s[t] += u;
        __syncthreads();
    }
    if (t < SNB) bsum[t] = s[t] - v;
    if (t == 255) off[NNODES] = s[255];
}

__global__ __launch_bounds__(256) void scan_final(const int* __restrict__ deg,
                                                  const int* __restrict__ bsum,
                                                  int* __restrict__ off,
                                                  int* __restrict__ cursor) {
    __shared__ int s[256];
    int t = threadIdx.x;
    int i = blockIdx.x * 256 + t;
    int v = (i < NNODES) ? deg[i] : 0;
    s[t] = v;
    __syncthreads();
    for (int d = 1; d < 256; d <<= 1) {
        int u = (t >= d) ? s[t - d] : 0;
        __syncthreads();
        s[t] += u;
        __syncthreads();
    }
    if (i < NNODES) {
        int e = bsum[blockIdx.x] + s[t] - v;
        off[i] = e;
        cursor[i] = e;
    }
}

__global__ __launch_bounds__(256) void fill_kernel(const int* __restrict__ ei,
                                                   int* __restrict__ cursor,
                                                   long long* __restrict__ csr) {
    int e = blockIdx.x * 256 + threadIdx.x;
    if (e < NEDGES) {
        int dst = __builtin_nontemporal_load(&ei[NEDGES + e]);
        int src = __builtin_nontemporal_load(&ei[e]);
        int p = atomicAdd(&cursor[dst], 1);
        __builtin_nontemporal_store((long long)(unsigned)src | ((long long)e << 32), &csr[p]);
    }
}

// ---------------- weight pre-pack into bf16 fragment layout ----------------
__global__ __launch_bounds__(256) void pack_weights(
    const float* __restrict__ Wmsg, const float* __restrict__ Wskip,
    const float* __restrict__ Wz, const float* __restrict__ Wr,
    const float* __restrict__ Wh, bfrag* __restrict__ pW)
{
    int id = blockIdx.x * 256 + threadIdx.x;
    if (id >= PW_TOT) return;
    const float* W = nullptr;
    int rem;
    bool conv = false;
    if (id < PW_Z)      { rem = id;           conv = true; }
    else if (id < PW_R) { rem = id - PW_Z;    W = Wz; }
    else if (id < PW_H) { rem = id - PW_R;    W = Wr; }
    else                { rem = id - PW_H;    W = Wh; }
    int kb   = rem >> 9;
    int t    = (rem >> 6) & 7;
    int lane = rem & 63;
    int col  = t * 16 + (lane & 15);
    int k0   = kb * 32 + ((lane >> 4) << 3);
    bfrag v;
    #pragma unroll
    for (int j = 0; j < 8; j++) {
        int k = k0 + j;
        float w;
        if (conv) w = (k < 160) ? Wmsg[k * DD + col] : Wskip[(k - 160) * DD + col];
        else      w = W[k * DD + col];
        v[j] = (short)f2bf(w);
    }
    pW[id] = v;
}

// ---------------- fused gather + MFMA node kernel ----------------
// Per block: 32 nodes. Phase 0: stage x (conv kb5-8) + H from global; gather
// S (edge-sum of x[src]) and T (edge-sum of ef) per node, one wave per 8 nodes,
// writing results straight into the LDS A-fragment slots (kb0-4). Then conv ->
// ReLU -> GRU, all MFMA as before.
__global__ __launch_bounds__(256) void node_fused(
    const float* __restrict__ x, const float* __restrict__ H,
    const float* __restrict__ ef,
    const long long* __restrict__ csr, const int* __restrict__ off,
    const bfrag* __restrict__ pW,
    const float* __restrict__ bconv, const float* __restrict__ bskip,
    const float* __restrict__ bz, const float* __restrict__ br,
    const float* __restrict__ bh,
    float* __restrict__ out)
{
    __shared__ short lclA[9 * 2 * 64 * 8];   // 18432 B
    __shared__ short lclG[4 * 2 * 64 * 8];   //  8192 B
    const int tid = threadIdx.x;
    const int n0 = blockIdx.x * 32;
    const int w    = tid >> 6;
    const int lane = tid & 63;

    // ---- stage x into conv kb5-8 (512 slots) ----
    for (int s = 640 + tid; s < 1152; s += 256) {
        int kb = s >> 7, mm = (s >> 6) & 1, cb = (s >> 4) & 3, r16 = s & 15;
        int row = mm * 16 + r16, gn = n0 + row;
        int k0 = kb * 32 + cb * 8;          // 160..280
        bfrag v;
        if (gn < NNODES) {
            const float* src = &x[(size_t)gn * DD + (k0 - 160)];
            float4 p0 = *(const float4*)src;
            float4 p1 = *(const float4*)(src + 4);
            v[0] = (short)f2bf(p0.x); v[1] = (short)f2bf(p0.y);
            v[2] = (short)f2bf(p0.z); v[3] = (short)f2bf(p0.w);
            v[4] = (short)f2bf(p1.x); v[5] = (short)f2bf(p1.y);
            v[6] = (short)f2bf(p1.z); v[7] = (short)f2bf(p1.w);
        } else {
            #pragma unroll
            for (int j = 0; j < 8; j++) v[j] = 0;
        }
        *(bfrag*)&lclA[((kb * 2 + mm) * 64 + (r16 | (cb << 4))) * 8] = v;
    }
    // ---- stage H (512 slots) into lclG ----
    for (int s = tid; s < 512; s += 256) {
        int kb = s >> 7, mm = (s >> 6) & 1, cb = (s >> 4) & 3, r16 = s & 15;
        int row = mm * 16 + r16, gn = n0 + row;
        int c0 = kb * 32 + cb * 8;
        bfrag v;
        if (gn < NNODES) {
            const float* src = &H[(size_t)gn * DD + c0];
            float4 p0 = *(const float4*)src;
            float4 p1 = *(const float4*)(src + 4);
            v[0] = (short)f2bf(p0.x); v[1] = (short)f2bf(p0.y);
            v[2] = (short)f2bf(p0.z); v[3] = (short)f2bf(p0.w);
            v[4] = (short)f2bf(p1.x); v[5] = (short)f2bf(p1.y);
            v[6] = (short)f2bf(p1.z); v[7] = (short)f2bf(p1.w);
        } else {
            #pragma unroll
            for (int j = 0; j < 8; j++) v[j] = 0;
        }
        *(bfrag*)&lclG[((kb * 2 + mm) * 64 + (r16 | (cb << 4))) * 8] = v;
    }

    // ---- gather: wave w handles nodes w*8 .. w*8+7 (R6-proven 8-deep loop) ----
    for (int nd = 0; nd < 8; nd++) {
        int row = w * 8 + nd;
        int gn = n0 + row;
        float2 acc = make_float2(0.0f, 0.0f);
        float accT = 0.0f;
        if (gn < NNODES) {
            int i0 = off[gn], i1 = off[gn + 1];
            int i = i0;
            for (; i + 8 <= i1; i += 8) {
                long long c[8];
                #pragma unroll
                for (int u = 0; u < 8; u++) c[u] = __builtin_nontemporal_load(&csr[i + u]);
                float2 v[8];
                #pragma unroll
                for (int u = 0; u < 8; u++) {
                    int src = (int)(unsigned)c[u];
                    v[u] = *reinterpret_cast<const float2*>(&x[(size_t)src * DD + lane * 2]);
                }
                float e[8];
                #pragma unroll
                for (int u = 0; u < 8; u++) {
                    int eid = (int)(c[u] >> 32);
                    e[u] = (lane < EDD) ? __builtin_nontemporal_load(&ef[(size_t)eid * EDD + lane]) : 0.0f;
                }
                #pragma unroll
                for (int u = 0; u < 8; u++) {
                    acc.x += v[u].x; acc.y += v[u].y; accT += e[u];
                }
            }
            for (; i + 2 <= i1; i += 2) {
                long long c0 = __builtin_nontemporal_load(&csr[i]);
                long long c1 = __builtin_nontemporal_load(&csr[i + 1]);
                int s0 = (int)(unsigned)c0, e0i = (int)(c0 >> 32);
                int s1 = (int)(unsigned)c1, e1i = (int)(c1 >> 32);
                float2 v0 = *reinterpret_cast<const float2*>(&x[(size_t)s0 * DD + lane * 2]);
                float2 v1 = *reinterpret_cast<const float2*>(&x[(size_t)s1 * DD + lane * 2]);
                float e0 = (lane < EDD) ? __builtin_nontemporal_load(&ef[(size_t)e0i * EDD + lane]) : 0.0f;
                float e1 = (lane < EDD) ? __builtin_nontemporal_load(&ef[(size_t)e1i * EDD + lane]) : 0.0f;
                acc.x += v0.x; acc.y += v0.y; accT += e0;
                acc.x += v1.x; acc.y += v1.y; accT += e1;
            }
            if (i < i1) {
                long long c0 = __builtin_nontemporal_load(&csr[i]);
                int s0 = (int)(unsigned)c0, e0i = (int)(c0 >> 32);
                float2 v0 = *reinterpret_cast<const float2*>(&x[(size_t)s0 * DD + lane * 2]);
                acc.x += v0.x; acc.y += v0.y;
                if (lane < EDD) accT += __builtin_nontemporal_load(&ef[(size_t)e0i * EDD + lane]);
            }
        }
        // write S fragment: cols 2*lane, 2*lane+1 of row -> kb0-3 slots
        int mm = row >> 4, r16 = row & 15;
        int kbS = lane >> 4, cbS = (lane >> 2) & 3, jS = (lane & 3) * 2;
        unsigned pk = ((unsigned)f2bf(acc.y) << 16) | (unsigned)f2bf(acc.x);
        *(unsigned*)&lclA[((kbS * 2 + mm) * 64 + (r16 | (cbS << 4))) * 8 + jS] = pk;
        // write T fragment: col lane (0..31) -> kb4 slot
        if (lane < EDD) {
            int cbT = (lane >> 3) & 3, jT = lane & 7;
            lclA[((4 * 2 + mm) * 64 + (r16 | (cbT << 4))) * 8 + jT] = (short)f2bf(accT);
        }
    }
    __syncthreads();

    const int m    = w & 1;
    const int ng   = (w >> 1) * 4;
    const int lc   = lane & 15;
    const int lr4  = (lane >> 4) * 4;

    // ---- conv GEMM: 9 kb, 4 n-tiles ----
    fx4 acc[4];
    #pragma unroll
    for (int t = 0; t < 4; t++) {
        int c = (ng + t) * 16 + lc;
        float b = bconv[c] + bskip[c];
        acc[t] = (fx4){b, b, b, b};
    }
    #pragma unroll
    for (int kb = 0; kb < 9; kb++) {
        bfrag a = *(const bfrag*)&lclA[((kb * 2 + m) * 64 + lane) * 8];
        #pragma unroll
        for (int t = 0; t < 4; t++) {
            bfrag b = pW[PW_CONV + (kb * 8 + ng + t) * 64 + lane];
            acc[t] = __builtin_amdgcn_mfma_f32_16x16x32_bf16(a, b, acc[t], 0, 0, 0);
        }
    }
    __syncthreads();

    // ---- ReLU -> h, write back as A-fragments into lclA kb0-3 ----
    #pragma unroll
    for (int t = 0; t < 4; t++) {
        int c  = (ng + t) * 16 + lc;
        int kb = c >> 5;
        int cb = (c >> 3) & 3;
        int j  = c & 7;
        #pragma unroll
        for (int reg = 0; reg < 4; reg++) {
            int row16 = lr4 + reg;
            float hv = fmaxf(acc[t][reg], 0.0f);
            lclA[((kb * 2 + m) * 64 + (row16 | (cb << 4))) * 8 + j] = (short)f2bf(hv);
        }
    }
    __syncthreads();

    // ---- z, r gates: K=256 ----
    fx4 az[4], ar[4];
    #pragma unroll
    for (int t = 0; t < 4; t++) {
        int c = (ng + t) * 16 + lc;
        float b1 = bz[c], b2 = br[c];
        az[t] = (fx4){b1, b1, b1, b1};
        ar[t] = (fx4){b2, b2, b2, b2};
    }
    #pragma unroll
    for (int kb = 0; kb < 8; kb++) {
        bfrag a = (kb < 4)
            ? *(const bfrag*)&lclA[((kb * 2 + m) * 64 + lane) * 8]
            : *(const bfrag*)&lclG[(((kb - 4) * 2 + m) * 64 + lane) * 8];
        #pragma unroll
        for (int t = 0; t < 4; t++) {
            bfrag wz = pW[PW_Z + (kb * 8 + ng + t) * 64 + lane];
            bfrag wr = pW[PW_R + (kb * 8 + ng + t) * 64 + lane];
            az[t] = __builtin_amdgcn_mfma_f32_16x16x32_bf16(a, wz, az[t], 0, 0, 0);
            ar[t] = __builtin_amdgcn_mfma_f32_16x16x32_bf16(a, wr, ar[t], 0, 0, 0);
        }
    }

    // ---- sigmoid; read H per-lane; rH ----
    float zv[4][4], Hv[4][4], rHv[4][4];
    #pragma unroll
    for (int t = 0; t < 4; t++) {
        int c  = (ng + t) * 16 + lc;
        int kb = c >> 5;
        int cb = (c >> 3) & 3;
        int j  = c & 7;
        #pragma unroll
        for (int reg = 0; reg < 4; reg++) {
            int row16 = lr4 + reg;
            zv[t][reg] = fast_sigmoid(az[t][reg]);
            float rv = fast_sigmoid(ar[t][reg]);
            float hH = bf2f((unsigned short)lclG[((kb * 2 + m) * 64 + (row16 | (cb << 4))) * 8 + j]);
            Hv[t][reg]  = hH;
            rHv[t][reg] = rv * hH;
        }
    }
    __syncthreads();

    // ---- overwrite lclG with rH fragments ----
    #pragma unroll
    for (int t = 0; t < 4; t++) {
        int c  = (ng + t) * 16 + lc;
        int kb = c >> 5;
        int cb = (c >> 3) & 3;
        int j  = c & 7;
        #pragma unroll
        for (int reg = 0; reg < 4; reg++) {
            int row16 = lr4 + reg;
            lclG[((kb * 2 + m) * 64 + (row16 | (cb << 4))) * 8 + j] = (short)f2bf(rHv[t][reg]);
        }
    }
    __syncthreads();

    // ---- h_tilde: K=256 ----
    fx4 ah[4];
    #pragma unroll
    for (int t = 0; t < 4; t++) {
        int c = (ng + t) * 16 + lc;
        float b = bh[c];
        ah[t] = (fx4){b, b, b, b};
    }
    #pragma unroll
    for (int kb = 0; kb < 8; kb++) {
        bfrag a = (kb < 4)
            ? *(const bfrag*)&lclA[((kb * 2 + m) * 64 + lane) * 8]
            : *(const bfrag*)&lclG[(((kb - 4) * 2 + m) * 64 + lane) * 8];
        #pragma unroll
        for (int t = 0; t < 4; t++) {
            bfrag wh = pW[PW_H + (kb * 8 + ng + t) * 64 + lane];
            ah[t] = __builtin_amdgcn_mfma_f32_16x16x32_bf16(a, wh, ah[t], 0, 0, 0);
        }
    }

    // ---- epilogue ----
    #pragma unroll
    for (int reg = 0; reg < 4; reg++) {
        int row = m * 16 + lr4 + reg;
        int gn = n0 + row;
        if (gn < NNODES) {
            #pragma unroll
            for (int t = 0; t < 4; t++) {
                int c = (ng + t) * 16 + lc;
                float ht = fast_tanh(ah[t][reg]);
                float zz = zv[t][reg];
                out[(size_t)gn * DD + c] = zz * Hv[t][reg] + (1.0f - zz) * ht;
            }
        }
    }
}

extern "C" void kernel_launch(void* const* d_in, const int* in_sizes, int n_in,
                              void* d_out, int out_size, void* d_ws, size_t ws_size,
                              hipStream_t stream) {
    const float* x     = (const float*)d_in[0];
    const float* ef    = (const float*)d_in[1];
    const float* Hst   = (const float*)d_in[2];
    const int*   ei    = (const int*)d_in[3];
    const float* Wmsg  = (const float*)d_in[4];
    const float* bconv = (const float*)d_in[5];
    const float* Wskip = (const float*)d_in[6];
    const float* bskip = (const float*)d_in[7];
    const float* Wz    = (const float*)d_in[8];
    const float* bz    = (const float*)d_in[9];
    const float* Wr    = (const float*)d_in[10];
    const float* br    = (const float*)d_in[11];
    const float* Wh    = (const float*)d_in[12];
    const float* bh    = (const float*)d_in[13];
    float* out = (float*)d_out;

    // workspace layout (16B alignment maintained)
    bfrag* pW  = (bfrag*)d_ws;                               // 270336 B
    int*   deg = (int*)((char*)d_ws + PW_TOT * 16);          // [N]
    int*   off = deg + NNODES;                               // [N+1]
    int*   cur = off + NNODES + 1;                           // [N+1]
    int*   bsum = cur + NNODES + 1;                          // [256]
    long long* csr = (long long*)(bsum + 256);               // [E] 6.4 MB (8B-aligned)

    (void)hipMemsetAsync(deg, 0, NNODES * sizeof(int), stream);

    pack_weights<<<(PW_TOT + 255) / 256, 256, 0, stream>>>(Wmsg, Wskip, Wz, Wr, Wh, pW);

    int nbE = (NEDGES + 255) / 256;
    count_kernel<<<nbE, 256, 0, stream>>>(ei, deg);
    scan_reduce<<<SNB, 256, 0, stream>>>(deg, bsum);
    scan_bsum<<<1, 256, 0, stream>>>(bsum, off);
    scan_final<<<SNB, 256, 0, stream>>>(deg, bsum, off, cur);
    fill_kernel<<<nbE, 256, 0, stream>>>(ei, cur, csr);

    int nb2 = (NNODES + 31) / 32;
    node_fused<<<nb2, 256, 0, stream>>>(x, Hst, ef, csr, off, pW, bconv, bskip,
                                        bz, br, bh, out);
}